// Round 2
// baseline (183.733 us; speedup 1.0000x reference)
//
#include <hip/hip_runtime.h>

// Smith-Waterman soft-DP, B=512, x: (512,151,151) f32, scalar output.
// a=b=150, m=150 slots, n_diag=299. Packed anti-diagonal wavefront.

#define NEG_INF (-1e30f)
#define GAP_OPEN (-5.0f)
#define GAP_EXTEND (-1.0f)

constexpr int A_DIM = 150;   // a = N-1
constexpr int MSLOT = 150;   // packed diagonal width
constexpr int NDIAG = 299;   // a + b - 1
constexpr int NROW  = 151;   // matrix row length

__global__ __launch_bounds__(192)
void sw_kernel(const float* __restrict__ x, float* __restrict__ part,
               float* __restrict__ out_atomic, int use_atomic) {
    const int b = blockIdx.x;
    const float* xb = x + (size_t)b * NROW * NROW;
    const int t = threadIdx.x;
    const int j = t;             // slot index

    // Two rotating diagonal buffers, slots stored at [1..150], sentinels at 0 and 151.
    __shared__ float hA[MSLOT + 2][3];
    __shared__ float hB[MSLOT + 2][3];

    for (int idx = t; idx < (MSLOT + 2) * 3; idx += blockDim.x) {
        (&hA[0][0])[idx] = NEG_INF;
        (&hB[0][0])[idx] = NEG_INF;
    }
    __syncthreads();

    float (*h2buf)[3] = hA;   // two diagonals back
    float (*h1buf)[3] = hB;   // one diagonal back

    // online logsumexp accumulator over this thread's cell scores
    float M = NEG_INF, S = 0.0f;

    for (int d = 0; d < NDIAG; ++d) {
        const int so = d & 1;   // smo[d] = d % 2 (a is even)
        if (j < MSLOT) {
            const int r = ((A_DIM - 1 + d) >> 1) - j;
            const int c = d - r;
            const bool valid = (r >= 0) & (r < A_DIM) & (c >= 0) & (c < A_DIM);
            float sx = NEG_INF, x2 = 0.0f;
            if (valid) {
                const int off = r * NROW + c;
                sx = xb[off];
                x2 = xb[off + NROW + 1];   // x[b, 1+r, 1+c]
            }
            const float h2v0 = h2buf[j + 1][0];
            const float h2v1 = h2buf[j + 1][1];
            const float h2v2 = h2buf[j + 1][2];
            const float h1v0 = h1buf[j + 1][0];
            const float h1v1 = h1buf[j + 1][1];
            const float h1v2 = h1buf[j + 1][2];
            const int nbidx = so ? j : j + 2;        // h1[j-1] or h1[j+1]
            const float n0 = h1buf[nbidx][0];
            const float n1 = h1buf[nbidx][1];
            const float n2 = h1buf[nbidx][2];

            float r0, r1, dn0, dn1, dn2;
            if (so) {   // odd diag: right uses h1_dn (j-1), down uses h1 (j)
                r0 = n0 + GAP_OPEN;  r1 = n1 + GAP_EXTEND;
                dn0 = h1v0 + GAP_OPEN; dn1 = h1v1 + GAP_OPEN; dn2 = h1v2 + GAP_EXTEND;
            } else {    // even diag: right uses h1 (j), down uses h1_up (j+1)
                r0 = h1v0 + GAP_OPEN; r1 = h1v1 + GAP_EXTEND;
                dn0 = n0 + GAP_OPEN; dn1 = n1 + GAP_OPEN; dn2 = n2 + GAP_EXTEND;
            }

            // align = lse(h2 ++ {0}) + sx
            const float am = fmaxf(fmaxf(h2v0, h2v1), fmaxf(h2v2, 0.0f));
            const float as = __expf(h2v0 - am) + __expf(h2v1 - am)
                           + __expf(h2v2 - am) + __expf(-am);
            const float ho0 = sx + am + __logf(as);
            // right = lse(r0, r1)
            const float rm = fmaxf(r0, r1);
            const float ho1 = rm + __logf(__expf(r0 - rm) + __expf(r1 - rm));
            // down = lse(dn0, dn1, dn2)
            const float dm = fmaxf(fmaxf(dn0, dn1), dn2);
            const float ho2 = dm + __logf(__expf(dn0 - dm) + __expf(dn1 - dm)
                                        + __expf(dn2 - dm));

            // write new diagonal into h2buf (own slot only; no cross-thread readers)
            h2buf[j + 1][0] = ho0;
            h2buf[j + 1][1] = ho1;
            h2buf[j + 1][2] = ho2;

            if (valid) {
                // score contributions for this cell: ho{0,1,2} + x[b,1+r,1+c]
                const float s0 = ho0 + x2, s1 = ho1 + x2, s2 = ho2 + x2;
                const float mx = fmaxf(fmaxf(s0, s1), s2);
                const float add = __expf(s0 - mx) + __expf(s1 - mx) + __expf(s2 - mx);
                const float Mn = fmaxf(M, mx);
                S = S * __expf(M - Mn) + add * __expf(mx - Mn);
                M = Mn;
            }
        }
        __syncthreads();
        float (*tmp)[3] = h2buf; h2buf = h1buf; h1buf = tmp;
    }

    // block-level online-lse reduction of (M, S) over 192 threads
    #pragma unroll
    for (int off = 32; off; off >>= 1) {
        const float Mo = __shfl_xor(M, off);
        const float So = __shfl_xor(S, off);
        const float Mn = fmaxf(M, Mo);
        S = S * __expf(M - Mn) + So * __expf(Mo - Mn);
        M = Mn;
    }
    __shared__ float wM[3], wS[3];
    const int wid = t >> 6, lane = t & 63;
    if (lane == 0) { wM[wid] = M; wS[wid] = S; }
    __syncthreads();
    if (t == 0) {
        float Mt = wM[0], St = wS[0];
        #pragma unroll
        for (int w = 1; w < 3; ++w) {
            const float Mn = fmaxf(Mt, wM[w]);
            St = St * __expf(Mt - Mn) + wS[w] * __expf(wM[w] - Mn);
            Mt = Mn;
        }
        const float val = Mt + __logf(St);
        if (use_atomic) atomicAdd(out_atomic, val);
        else            part[b] = val;
    }
}

__global__ __launch_bounds__(256)
void final_reduce(const float* __restrict__ part, float* __restrict__ out) {
    const int t = threadIdx.x;
    float v = part[t] + part[t + 256];
    #pragma unroll
    for (int off = 32; off; off >>= 1) v += __shfl_xor(v, off);
    __shared__ float ws[4];
    if ((t & 63) == 0) ws[t >> 6] = v;
    __syncthreads();
    if (t == 0) out[0] = ws[0] + ws[1] + ws[2] + ws[3];
}

extern "C" void kernel_launch(void* const* d_in, const int* in_sizes, int n_in,
                              void* d_out, int out_size, void* d_ws, size_t ws_size,
                              hipStream_t stream) {
    const float* x = (const float*)d_in[0];
    float* out = (float*)d_out;

    if (ws_size >= 512 * sizeof(float)) {
        float* part = (float*)d_ws;
        sw_kernel<<<512, 192, 0, stream>>>(x, part, nullptr, 0);
        final_reduce<<<1, 256, 0, stream>>>(part, out);
    } else {
        hipMemsetAsync(out, 0, sizeof(float), stream);
        sw_kernel<<<512, 192, 0, stream>>>(x, nullptr, out, 1);
    }
}